// Round 2
// baseline (9630.617 us; speedup 1.0000x reference)
//
#include <hip/hip_runtime.h>

// ---------------------------------------------------------------------------
// Stacked BiLSTM autoencoder, fp32.
//   B=512, T=256, F=64, N=128
//   e1: BiLSTM in=64  u=128 -> h1 (B,T,256)
//   e2: 2x LSTM in=256 u=64, keep last(fwd)/first(bwd) -> z (B,128)
//   d1: BiLSTM in=128 (z broadcast over T) u=64 -> h2 (B,T,128)
//   d2: BiLSTM in=128 u=128 -> h3 (B,T,256)
//   dense: h3 @ Wd + bd -> out (B,T,64)
//
// Recurrence kernel: one block per (direction, 8-batch tile). Per step:
//   z = bias + [x_t ; h] @ [W;U]  (weights streamed from L2, v in LDS),
//   gate elementwise, h/c update, h -> LDS (+ global).
// d1: input is constant over t -> x@W folded into per-block prologue (BCAST).
// e2: only the final h is needed (LASTONLY).
// ws guard: if d_ws is smaller than the 192.2 MiB we need, launch nothing
// (clean wrong-answer signal instead of an OOB store crashing the container).
// ---------------------------------------------------------------------------

#define THREADS 512

__device__ __forceinline__ float sigf(float x) { return 1.0f / (1.0f + __expf(-x)); }

template<int IN, int UH, bool BCAST, bool LASTONLY, int BT>
__global__ __launch_bounds__(THREADS, 1)
void lstm_stage(const float* __restrict__ xin, const int xfd,
                const float* __restrict__ Wf, const float* __restrict__ Uf, const float* __restrict__ bf,
                const float* __restrict__ Wb, const float* __restrict__ Ub, const float* __restrict__ bb,
                float* __restrict__ out, const int T)
{
    constexpr int NCOL = 4 * UH;            // gate columns
    constexpr int G    = THREADS / NCOL;    // batch groups across threads (1 or 2)
    constexpr int BPG  = BT / G;            // batches per thread in the GEMM
    constexpr int PPT  = (BT * UH) / THREADS; // (batch,unit) pairs per thread
    static_assert(NCOL * G == THREADS, "thread/col mismatch");
    static_assert(BT % G == 0, "batch split");
    static_assert((BT * UH) % THREADS == 0, "pair split");
    static_assert(IN % 4 == 0 && UH % 4 == 0, "vec4");

    const int  dir = blockIdx.y;
    const bool rev = (dir != 0);
    const float* __restrict__ W    = dir ? Wb : Wf;
    const float* __restrict__ Uw   = dir ? Ub : Uf;
    const float* __restrict__ bias = dir ? bb : bf;

    const int b0    = blockIdx.x * BT;
    const int tid   = threadIdx.x;
    const int col   = tid % NCOL;
    const int bbase = (tid / NCOL) * BPG;

    __shared__ float v[BT][IN + UH];   // [x_t ; h]
    __shared__ float zb[BT][NCOL];     // pre-activation gates

    // h := 0
    for (int idx = tid; idx < BT * UH; idx += THREADS)
        v[idx / UH][IN + (idx % UH)] = 0.0f;
    // BCAST: load the (time-constant) input once
    if (BCAST) {
        for (int idx = tid; idx < BT * IN; idx += THREADS)
            v[idx / IN][idx % IN] = xin[(size_t)(b0 + idx / IN) * IN + (idx % IN)];
    }

    float acc0[BPG];
    #pragma unroll
    for (int i = 0; i < BPG; ++i) acc0[i] = bias[col];

    __syncthreads();

    if (BCAST) {
        // fold x @ W into acc0 once (input does not change over t)
        for (int k = 0; k < IN; k += 4) {
            const float* M = W + (size_t)k * NCOL + col;
            const float w0 = M[0], w1 = M[NCOL], w2 = M[2 * NCOL], w3 = M[3 * NCOL];
            #pragma unroll
            for (int i = 0; i < BPG; ++i) {
                const float4 vv = *reinterpret_cast<const float4*>(&v[bbase + i][k]);
                acc0[i] = fmaf(vv.x, w0, acc0[i]);
                acc0[i] = fmaf(vv.y, w1, acc0[i]);
                acc0[i] = fmaf(vv.z, w2, acc0[i]);
                acc0[i] = fmaf(vv.w, w3, acc0[i]);
            }
        }
    }

    float cst[PPT];
    #pragma unroll
    for (int q = 0; q < PPT; ++q) cst[q] = 0.0f;

    for (int p = 0; p < T; ++p) {
        const int t = rev ? (T - 1 - p) : p;

        if (!BCAST) {
            // stream x_t tile into LDS (disjoint from h region; barrier below orders it)
            for (int idx = tid; idx < BT * IN; idx += THREADS) {
                const int b = idx / IN, f = idx % IN;
                v[b][f] = xin[((size_t)(b0 + b) * T + t) * xfd + f];
            }
        }
        __syncthreads();   // x_t visible; h from previous step visible

        float acc[BPG];
        #pragma unroll
        for (int i = 0; i < BPG; ++i) acc[i] = acc0[i];

        if (!BCAST) {
            #pragma unroll 2
            for (int k = 0; k < IN; k += 4) {
                const float* M = W + (size_t)k * NCOL + col;
                const float w0 = M[0], w1 = M[NCOL], w2 = M[2 * NCOL], w3 = M[3 * NCOL];
                #pragma unroll
                for (int i = 0; i < BPG; ++i) {
                    const float4 vv = *reinterpret_cast<const float4*>(&v[bbase + i][k]);
                    acc[i] = fmaf(vv.x, w0, acc[i]);
                    acc[i] = fmaf(vv.y, w1, acc[i]);
                    acc[i] = fmaf(vv.z, w2, acc[i]);
                    acc[i] = fmaf(vv.w, w3, acc[i]);
                }
            }
        }
        #pragma unroll 2
        for (int k = 0; k < UH; k += 4) {
            const float* M = Uw + (size_t)k * NCOL + col;
            const float w0 = M[0], w1 = M[NCOL], w2 = M[2 * NCOL], w3 = M[3 * NCOL];
            #pragma unroll
            for (int i = 0; i < BPG; ++i) {
                const float4 vv = *reinterpret_cast<const float4*>(&v[bbase + i][IN + k]);
                acc[i] = fmaf(vv.x, w0, acc[i]);
                acc[i] = fmaf(vv.y, w1, acc[i]);
                acc[i] = fmaf(vv.z, w2, acc[i]);
                acc[i] = fmaf(vv.w, w3, acc[i]);
            }
        }
        #pragma unroll
        for (int i = 0; i < BPG; ++i) zb[bbase + i][col] = acc[i];

        __syncthreads();   // zb visible; all v reads of this step done

        #pragma unroll
        for (int q = 0; q < PPT; ++q) {
            const int pr = tid + q * THREADS;
            const int b = pr / UH, jj = pr % UH;
            const float iv = sigf(zb[b][jj]);
            const float fv = sigf(zb[b][UH + jj]);
            const float gv = fmaxf(zb[b][2 * UH + jj], 0.0f);
            const float ov = sigf(zb[b][3 * UH + jj]);
            const float c  = fv * cst[q] + iv * gv;
            cst[q] = c;
            const float h  = ov * fmaxf(c, 0.0f);
            v[b][IN + jj] = h;   // next step's recurrent input
            if (!LASTONLY) {
                out[((size_t)(b0 + b) * T + t) * (2 * UH) + (size_t)dir * UH + jj] = h;
            } else if (p == T - 1) {
                // fwd: h at t=T-1; bwd: h at t=0 (== final state of reversed scan)
                out[(size_t)(b0 + b) * (2 * UH) + (size_t)dir * UH + jj] = h;
            }
        }
        // no trailing barrier: top-of-loop barrier orders h writes vs next GEMM
    }
}

// out(rows,64) = h(rows,256) @ Wd(256,64) + bd
__global__ __launch_bounds__(256, 1)
void dense_out(const float* __restrict__ h, const float* __restrict__ Wd,
               const float* __restrict__ bd, float* __restrict__ out, const int rows)
{
    const int tid = threadIdx.x;
    const int lc  = (tid & 15) * 4;                  // 4 output cols per thread
    const size_t row = (size_t)blockIdx.x * 16 + (tid >> 4);
    if (row >= (size_t)rows) return;
    const float* hr = h + row * 256;
    float4 a;
    a.x = bd[lc]; a.y = bd[lc + 1]; a.z = bd[lc + 2]; a.w = bd[lc + 3];
    #pragma unroll 4
    for (int k = 0; k < 256; k += 4) {
        const float4 hv = *reinterpret_cast<const float4*>(&hr[k]);
        const float4 w0 = *reinterpret_cast<const float4*>(&Wd[(size_t)(k + 0) * 64 + lc]);
        const float4 w1 = *reinterpret_cast<const float4*>(&Wd[(size_t)(k + 1) * 64 + lc]);
        const float4 w2 = *reinterpret_cast<const float4*>(&Wd[(size_t)(k + 2) * 64 + lc]);
        const float4 w3 = *reinterpret_cast<const float4*>(&Wd[(size_t)(k + 3) * 64 + lc]);
        a.x = fmaf(hv.x, w0.x, a.x); a.y = fmaf(hv.x, w0.y, a.y); a.z = fmaf(hv.x, w0.z, a.z); a.w = fmaf(hv.x, w0.w, a.w);
        a.x = fmaf(hv.y, w1.x, a.x); a.y = fmaf(hv.y, w1.y, a.y); a.z = fmaf(hv.y, w1.z, a.z); a.w = fmaf(hv.y, w1.w, a.w);
        a.x = fmaf(hv.z, w2.x, a.x); a.y = fmaf(hv.z, w2.y, a.y); a.z = fmaf(hv.z, w2.z, a.z); a.w = fmaf(hv.z, w2.w, a.w);
        a.x = fmaf(hv.w, w3.x, a.x); a.y = fmaf(hv.w, w3.y, a.y); a.z = fmaf(hv.w, w3.z, a.z); a.w = fmaf(hv.w, w3.w, a.w);
    }
    *reinterpret_cast<float4*>(&out[row * 64 + lc]) = a;
}

extern "C" void kernel_launch(void* const* d_in, const int* in_sizes, int n_in,
                              void* d_out, int out_size, void* d_ws, size_t ws_size,
                              hipStream_t stream)
{
    (void)in_sizes; (void)n_in; (void)out_size;
    constexpr int B = 512, T = 256;
    constexpr int BT = 8;

    // workspace layout (floats): h1/h3 share a region (h1 dead after e2)
    const size_t n_h1 = (size_t)B * T * 256;      // 33,554,432 fl
    const size_t n_h2 = (size_t)B * T * 128;      // 16,777,216 fl
    const size_t n_zv = (size_t)B * 128;          //     65,536 fl
    const size_t need_bytes = (n_h1 + n_h2 + n_zv) * sizeof(float);  // ~192.2 MiB
    if (ws_size < need_bytes) {
        // Workspace too small: launching would write OOB and could kill the
        // container. Do nothing -> clean "incorrect result" diagnostic.
        return;
    }

    const float* x    = (const float*)d_in[0];
    const float* e1fW = (const float*)d_in[1];
    const float* e1fU = (const float*)d_in[2];
    const float* e1fb = (const float*)d_in[3];
    const float* e1bW = (const float*)d_in[4];
    const float* e1bU = (const float*)d_in[5];
    const float* e1bb = (const float*)d_in[6];
    const float* e2fW = (const float*)d_in[7];
    const float* e2fU = (const float*)d_in[8];
    const float* e2fb = (const float*)d_in[9];
    const float* e2bW = (const float*)d_in[10];
    const float* e2bU = (const float*)d_in[11];
    const float* e2bb = (const float*)d_in[12];
    const float* d1fW = (const float*)d_in[13];
    const float* d1fU = (const float*)d_in[14];
    const float* d1fb = (const float*)d_in[15];
    const float* d1bW = (const float*)d_in[16];
    const float* d1bU = (const float*)d_in[17];
    const float* d1bb = (const float*)d_in[18];
    const float* d2fW = (const float*)d_in[19];
    const float* d2fU = (const float*)d_in[20];
    const float* d2fb = (const float*)d_in[21];
    const float* d2bW = (const float*)d_in[22];
    const float* d2bU = (const float*)d_in[23];
    const float* d2bb = (const float*)d_in[24];
    const float* Wd   = (const float*)d_in[25];
    const float* bd   = (const float*)d_in[26];
    float* out = (float*)d_out;

    float* ws = (float*)d_ws;
    float* h1 = ws;
    float* h2 = ws + n_h1;
    float* zv = h2 + n_h2;
    float* h3 = h1;                               // reuse (h1 dead after e2)

    const dim3 grid(B / BT, 2), blk(THREADS);

    // e1: in=64, u=128, full sequence -> h1
    lstm_stage<64, 128, false, false, BT><<<grid, blk, 0, stream>>>(
        x, 64, e1fW, e1fU, e1fb, e1bW, e1bU, e1bb, h1, T);
    // e2: in=256, u=64, final state only -> z (B,128)
    lstm_stage<256, 64, false, true, BT><<<grid, blk, 0, stream>>>(
        h1, 256, e2fW, e2fU, e2fb, e2bW, e2bU, e2bb, zv, T);
    // d1: in=128 (z, time-broadcast), u=64 -> h2
    lstm_stage<128, 64, true, false, BT><<<grid, blk, 0, stream>>>(
        zv, 128, d1fW, d1fU, d1fb, d1bW, d1bU, d1bb, h2, T);
    // d2: in=128, u=128 -> h3
    lstm_stage<128, 128, false, false, BT><<<grid, blk, 0, stream>>>(
        h2, 128, d2fW, d2fU, d2fb, d2bW, d2bU, d2bb, h3, T);
    // dense head
    dense_out<<<(B * T + 15) / 16, 256, 0, stream>>>(h3, Wd, bd, out, B * T);
}